// Round 6
// baseline (1502.176 us; speedup 1.0000x reference)
//
#include <hip/hip_runtime.h>
#include <cstddef>
#include <cstdint>

#define NB 64
#define ND 1024
#define NO 31
#define NSTEPS 16
#define KS 62            // k-splits (k-chunk = 512 k-units, never crosses an opcode)
#define KT32 992         // total K32 steps = 31*1024/32
#define KC32 16          // K32 steps per block
#define GRID 496         // 8 n-tiles x 62 k-splits; 80 KB LDS -> 2 blocks/CU resident

typedef _Float16 half8 __attribute__((ext_vector_type(8)));
typedef float floatx4 __attribute__((ext_vector_type(4)));

// rolling waits: vmcnt(N), lgkm/exp don't-care (gfx9 encoding; validated r5)
__device__ __forceinline__ void wait_vm2() {
    __builtin_amdgcn_s_waitcnt(0x0f72);   // vmcnt(2)
    __builtin_amdgcn_sched_barrier(0);
}
__device__ __forceinline__ void wait_vm0() {
    __builtin_amdgcn_s_waitcnt(0x0f70);   // vmcnt(0)
    __builtin_amdgcn_sched_barrier(0);
}
// async global->LDS DMA, 16 B/lane; lane i lands at lds_base + 16*i
__device__ __forceinline__ void gld_lds16(const _Float16* g, _Float16* l) {
    __builtin_amdgcn_global_load_lds(
        (__attribute__((address_space(1))) void*)g,
        (__attribute__((address_space(3))) void*)l, 16, 0, 0);
}

// ---------------- softmax over opcode logits: W[b][t][o] ----------------
__global__ void softmax_k(const float* __restrict__ logits, float* __restrict__ W) {
    int row = blockIdx.x * blockDim.x + threadIdx.x;  // row = b*16 + t
    if (row >= NB * NSTEPS) return;
    const float* x = logits + (size_t)row * NO;
    float m = -1e30f;
    for (int o = 0; o < NO; ++o) m = fmaxf(m, x[o]);
    float e[NO]; float s = 0.f;
    for (int o = 0; o < NO; ++o) { e[o] = expf(x[o] - m); s += e[o]; }
    float inv = 1.0f / s;
    float* wo = W + (size_t)row * NO;
    for (int o = 0; o < NO; ++o) wo[o] = e[o] * inv;
}

// ---- kconv: Ktf fragment-ordered fp16 B (layout as rounds 1-5) ----
__global__ void kconv_k(const float* __restrict__ K, _Float16* __restrict__ Ktf) {
    int gid = blockIdx.x * 256 + threadIdx.x;   // total = 64*992*64 = 4,063,232
    int l  = gid & 63;
    int kt = (gid >> 6) % KT32;
    int ns = gid / (64 * KT32);
    int kbase = kt * 32 + (l >> 4) * 8;         // o constant across the 8 j's
    int n  = ns * 16 + (l & 15);
    int o  = kbase >> 10;
    int d0 = kbase & 1023;
    const float* src = K + ((size_t)o << 20) + (size_t)d0 * ND + n;
    half8 v;
    #pragma unroll
    for (int j = 0; j < 8; ++j) v[j] = (_Float16)src[(size_t)j * ND];
    *(half8*)(Ktf + (size_t)gid * 8) = v;
}

// ---- grid barrier: padded cells (1/cacheline), lane-parallel collector ----
// cells[i*16]: arrival counter for blocks with blk&63==i (8 for i<48, else 7).
// flag at cells[1024] (separate line). barid strictly increasing.
__device__ __forceinline__ void gridbar(unsigned* cells, int blk, unsigned barid) {
    __syncthreads();                       // drains vmcnt before arrival
    unsigned* flag = cells + 1024;
    int tid = threadIdx.x;
    if (tid < 64) {
        if (tid == 0) {
            __threadfence();               // release: P/h writes visible device-wide
            __hip_atomic_fetch_add(cells + (blk & 63) * 16, 1u,
                                   __ATOMIC_RELEASE, __HIP_MEMORY_SCOPE_AGENT);
        }
        if (blk == 0) {
            unsigned target = barid * ((tid < 48) ? 8u : 7u);
            for (;;) {
                unsigned v = __hip_atomic_load(cells + tid * 16, __ATOMIC_RELAXED,
                                               __HIP_MEMORY_SCOPE_AGENT);
                if (__all((int)(v >= target))) break;
                __builtin_amdgcn_s_sleep(1);
            }
            if (tid == 0)
                __hip_atomic_store(flag, barid, __ATOMIC_RELEASE,
                                   __HIP_MEMORY_SCOPE_AGENT);
        } else if (tid == 0) {
            while (__hip_atomic_load(flag, __ATOMIC_RELAXED,
                                     __HIP_MEMORY_SCOPE_AGENT) < barid)
                __builtin_amdgcn_s_sleep(2);
        }
        if (tid == 0) __threadfence();     // acquire: invalidate stale caches
    }
    __syncthreads();
}

// ---- persistent kernel: all 16 steps, round-5 DMA K-loop, no reg B-cache ----
__global__ __launch_bounds__(256, 2) void persist_k(
    const float* __restrict__ signal, const _Float16* __restrict__ Ktf,
    const float* __restrict__ W, const float* __restrict__ operands,
    float* __restrict__ P, float* __restrict__ h0buf, float* __restrict__ h1buf,
    float* __restrict__ out, unsigned* __restrict__ cells)
{
    __shared__ _Float16 lds_a[64 * 512];        // 64 KB frag-ordered A
    __shared__ _Float16 lds_b[2][8][512];       // 16 KB: 2 bufs x 8 units x 1 KB
    const int blk = blockIdx.x;
    const int nb = blk & 7, ks = blk >> 3;
    const int tid = threadIdx.x;
    const int l = tid & 63, w = tid >> 6;
    const int o = ks >> 1, d_base = (ks & 1) * 512;
    const int ml = l & 15, q = l >> 4;
    const int ns0 = nb * 8 + w * 2;
    const size_t kt0 = (size_t)ks * KC32;
    const int ab = tid >> 2, au = tid & 3;

    const _Float16* gB0 = Ktf + (((size_t)ns0 * KT32 + kt0) << 9) + (l << 3);
    const _Float16* gB1 = Ktf + ((((size_t)ns0 + 1) * KT32 + kt0) << 9) + (l << 3);
    float* Pks = P + (size_t)ks * (NB * ND);
    const half8* Ap = (const half8*)lds_a;

    for (int t = 0; t < NSTEPS; ++t) {
        const float* hsrc = (t == 0) ? signal : ((t & 1) ? h0buf : h1buf);

        // prefetch B chunks 0,1 (drained by the post-A-stage __syncthreads)
        gld_lds16(gB0,       &lds_b[0][2 * w][0]);
        gld_lds16(gB1,       &lds_b[0][2 * w + 1][0]);
        gld_lds16(gB0 + 512, &lds_b[1][2 * w][0]);
        gld_lds16(gB1 + 512, &lds_b[1][2 * w + 1][0]);

        // ---- stage A: fp32 h * w -> fp16, frag-ordered ----
        {
            float wv = W[((size_t)ab * NSTEPS + t) * NO + o];
            const float* hb = hsrc + (size_t)ab * ND + d_base;
            #pragma unroll 4
            for (int li = 0; li < 16; ++li) {
                int p = li * 4 + au;
                float4 x0 = *(const float4*)(hb + p * 8);
                float4 x1 = *(const float4*)(hb + p * 8 + 4);
                half8 v;
                v[0] = (_Float16)(x0.x * wv); v[1] = (_Float16)(x0.y * wv);
                v[2] = (_Float16)(x0.z * wv); v[3] = (_Float16)(x0.w * wv);
                v[4] = (_Float16)(x1.x * wv); v[5] = (_Float16)(x1.y * wv);
                v[6] = (_Float16)(x1.z * wv); v[7] = (_Float16)(x1.w * wv);
                *(half8*)&lds_a[(size_t)(p * 64 + ab) * 8] = v;
            }
        }
        __syncthreads();

        floatx4 acc[2][4] = {};
        #pragma unroll
        for (int s = 0; s < 15; ++s) {
            wait_vm2();
            int buf = s & 1;
            half8 b0 = *(const half8*)&lds_b[buf][2 * w][l * 8];
            half8 b1 = *(const half8*)&lds_b[buf][2 * w + 1][l * 8];
            int abase = (s * 4 + q) * 64 + ml;
            half8 a0 = Ap[abase];
            half8 a1 = Ap[abase + 16];
            half8 a2 = Ap[abase + 32];
            half8 a3 = Ap[abase + 48];
            acc[0][0] = __builtin_amdgcn_mfma_f32_16x16x32_f16(a0, b0, acc[0][0], 0, 0, 0);
            acc[0][1] = __builtin_amdgcn_mfma_f32_16x16x32_f16(a1, b0, acc[0][1], 0, 0, 0);
            acc[0][2] = __builtin_amdgcn_mfma_f32_16x16x32_f16(a2, b0, acc[0][2], 0, 0, 0);
            acc[0][3] = __builtin_amdgcn_mfma_f32_16x16x32_f16(a3, b0, acc[0][3], 0, 0, 0);
            acc[1][0] = __builtin_amdgcn_mfma_f32_16x16x32_f16(a0, b1, acc[1][0], 0, 0, 0);
            acc[1][1] = __builtin_amdgcn_mfma_f32_16x16x32_f16(a1, b1, acc[1][1], 0, 0, 0);
            acc[1][2] = __builtin_amdgcn_mfma_f32_16x16x32_f16(a2, b1, acc[1][2], 0, 0, 0);
            acc[1][3] = __builtin_amdgcn_mfma_f32_16x16x32_f16(a3, b1, acc[1][3], 0, 0, 0);
            if (s < 14) {
                gld_lds16(gB0 + (size_t)(s + 2) * 512, &lds_b[buf][2 * w][0]);
                gld_lds16(gB1 + (size_t)(s + 2) * 512, &lds_b[buf][2 * w + 1][0]);
            }
        }
        {   // peeled s = 15
            wait_vm0();
            half8 b0 = *(const half8*)&lds_b[1][2 * w][l * 8];
            half8 b1 = *(const half8*)&lds_b[1][2 * w + 1][l * 8];
            int abase = (15 * 4 + q) * 64 + ml;
            half8 a0 = Ap[abase];
            half8 a1 = Ap[abase + 16];
            half8 a2 = Ap[abase + 32];
            half8 a3 = Ap[abase + 48];
            acc[0][0] = __builtin_amdgcn_mfma_f32_16x16x32_f16(a0, b0, acc[0][0], 0, 0, 0);
            acc[0][1] = __builtin_amdgcn_mfma_f32_16x16x32_f16(a1, b0, acc[0][1], 0, 0, 0);
            acc[0][2] = __builtin_amdgcn_mfma_f32_16x16x32_f16(a2, b0, acc[0][2], 0, 0, 0);
            acc[0][3] = __builtin_amdgcn_mfma_f32_16x16x32_f16(a3, b0, acc[0][3], 0, 0, 0);
            acc[1][0] = __builtin_amdgcn_mfma_f32_16x16x32_f16(a0, b1, acc[1][0], 0, 0, 0);
            acc[1][1] = __builtin_amdgcn_mfma_f32_16x16x32_f16(a1, b1, acc[1][1], 0, 0, 0);
            acc[1][2] = __builtin_amdgcn_mfma_f32_16x16x32_f16(a2, b1, acc[1][2], 0, 0, 0);
            acc[1][3] = __builtin_amdgcn_mfma_f32_16x16x32_f16(a3, b1, acc[1][3], 0, 0, 0);
        }

        // ---- write partial (C/D: col = l&15, row = (l>>4)*4 + r) ----
        #pragma unroll
        for (int nsub = 0; nsub < 2; ++nsub) {
            int n = (ns0 + nsub) * 16 + ml;
            #pragma unroll
            for (int mt = 0; mt < 4; ++mt) {
                #pragma unroll
                for (int r = 0; r < 4; ++r) {
                    int b = mt * 16 + q * 4 + r;
                    Pks[(size_t)b * ND + n] = acc[nsub][mt][r];
                }
            }
        }

        gridbar(cells, blk, (unsigned)(2 * t + 1));

        // ---- update: blocks 0..63, block b = batch row, float4/thread ----
        if (blk < NB) {
            const int b = blk;
            float gl = operands[((size_t)b * NSTEPS + t) * 4 + 3];
            float g  = 1.0f / (1.0f + expf(-gl));
            const float* prow = P + (size_t)b * ND + tid * 4;
            float sx = 0.f, sy = 0.f, sz = 0.f, sw = 0.f;
            #pragma unroll 8
            for (int k2 = 0; k2 < KS; ++k2) {
                float4 v = *(const float4*)(prow + (size_t)k2 * (NB * ND));
                sx += v.x; sy += v.y; sz += v.z; sw += v.w;
            }
            float4 hv = *(const float4*)(hsrc + (size_t)b * ND + tid * 4);
            float* hdst = (t == NSTEPS - 1) ? out : ((t & 1) ? h1buf : h0buf);
            float4 ov;
            ov.x = g * sx + (1.f - g) * hv.x;
            ov.y = g * sy + (1.f - g) * hv.y;
            ov.z = g * sz + (1.f - g) * hv.z;
            ov.w = g * sw + (1.f - g) * hv.w;
            *(float4*)(hdst + (size_t)b * ND + tid * 4) = ov;
        }

        if (t < NSTEPS - 1)
            gridbar(cells, blk, (unsigned)(2 * t + 2));
    }
}

extern "C" void kernel_launch(void* const* d_in, const int* in_sizes, int n_in,
                              void* d_out, int out_size, void* d_ws, size_t ws_size,
                              hipStream_t stream)
{
    const float* logits   = (const float*)d_in[0];  // (64,16,31)
    const float* operands = (const float*)d_in[1];  // (64,16,4)
    const float* signal   = (const float*)d_in[2];  // (64,1024)
    const float* opk      = (const float*)d_in[3];  // (31,1024,1024)
    float* out = (float*)d_out;
    char* ws = (char*)d_ws;

    size_t offCNT = 0;                                 // 8 KB barrier state
    size_t offW   = 8192;                              // W: 126976 B
    size_t offP   = offW + 126976;                     // P: 62*64*1024*4
    size_t offH   = offP + (size_t)KS * NB * ND * 4;
    size_t offK   = offH + 2ull * NB * ND * 4;         // Ktf: 62 MB fp16

    unsigned* cells = (unsigned*)(ws + offCNT);
    float*    W  = (float*)(ws + offW);
    float*    P  = (float*)(ws + offP);
    float*    h0 = (float*)(ws + offH);
    float*    h1 = h0 + NB * ND;
    _Float16* Ktf = (_Float16*)(ws + offK);

    hipMemsetAsync(ws, 0, 8192, stream);   // zero barrier cells + flag
    softmax_k<<<dim3(4), 256, 0, stream>>>(logits, W);
    kconv_k<<<dim3(15872), 256, 0, stream>>>(opk, Ktf);
    persist_k<<<dim3(GRID), 256, 0, stream>>>(signal, Ktf, W, operands,
                                              P, h0, h1, out, cells);
}

// Round 7
// 782.243 us; speedup vs baseline: 1.9203x; 1.9203x over previous
//
#include <hip/hip_runtime.h>
#include <cstddef>
#include <cstdint>

#define NB 64
#define ND 1024
#define NO 31
#define NSTEPS 16
#define KS 62            // k-splits (k-chunk = 512, never crosses an opcode)
#define KT32 992         // total K32 steps = 31*1024/32
#define KC32 16          // K32 steps per block
#define GRID 496         // 8 n-tiles x 62 k-splits; 80 KB LDS -> 2 blocks/CU
#define CELL 16          // u32 stride between flag cells (64 B line each)

typedef _Float16 half8 __attribute__((ext_vector_type(8)));
typedef float floatx4 __attribute__((ext_vector_type(4)));

__device__ __forceinline__ void wait_vm2() {
    __builtin_amdgcn_s_waitcnt(0x0f72);   // vmcnt(2)
    __builtin_amdgcn_sched_barrier(0);
}
__device__ __forceinline__ void wait_vm0() {
    __builtin_amdgcn_s_waitcnt(0x0f70);   // vmcnt(0)
    __builtin_amdgcn_sched_barrier(0);
}
__device__ __forceinline__ void gld_lds16(const _Float16* g, _Float16* l) {
    __builtin_amdgcn_global_load_lds(
        (__attribute__((address_space(1))) void*)g,
        (__attribute__((address_space(3))) void*)l, 16, 0, 0);
}
__device__ __forceinline__ unsigned ld_rlx(const unsigned* p) {
    return __hip_atomic_load(p, __ATOMIC_RELAXED, __HIP_MEMORY_SCOPE_AGENT);
}
__device__ __forceinline__ void add_rlx(unsigned* p) {
    __hip_atomic_fetch_add(p, 1u, __ATOMIC_RELAXED, __HIP_MEMORY_SCOPE_AGENT);
}
// coherent (write-through to coherence point) stores — no wbl2 needed for release
__device__ __forceinline__ void stg_f(float* p, float v) {
    __hip_atomic_store(p, v, __ATOMIC_RELAXED, __HIP_MEMORY_SCOPE_AGENT);
}
__device__ __forceinline__ void stg_f2(float* p, float2 v) {
    union { unsigned long long u; float2 f; } c; c.f = v;
    __hip_atomic_store((unsigned long long*)p, c.u,
                       __ATOMIC_RELAXED, __HIP_MEMORY_SCOPE_AGENT);
}

// ---------------- softmax over opcode logits: W[b][t][o] ----------------
__global__ void softmax_k(const float* __restrict__ logits, float* __restrict__ W) {
    int row = blockIdx.x * blockDim.x + threadIdx.x;
    if (row >= NB * NSTEPS) return;
    const float* x = logits + (size_t)row * NO;
    float m = -1e30f;
    for (int o = 0; o < NO; ++o) m = fmaxf(m, x[o]);
    float e[NO]; float s = 0.f;
    for (int o = 0; o < NO; ++o) { e[o] = expf(x[o] - m); s += e[o]; }
    float inv = 1.0f / s;
    float* wo = W + (size_t)row * NO;
    for (int o = 0; o < NO; ++o) wo[o] = e[o] * inv;
}

// ---- kconv: Ktf fragment-ordered fp16 B (layout as rounds 1-6) ----
__global__ void kconv_k(const float* __restrict__ K, _Float16* __restrict__ Ktf) {
    int gid = blockIdx.x * 256 + threadIdx.x;
    int l  = gid & 63;
    int kt = (gid >> 6) % KT32;
    int ns = gid / (64 * KT32);
    int kbase = kt * 32 + (l >> 4) * 8;
    int n  = ns * 16 + (l & 15);
    int o  = kbase >> 10;
    int d0 = kbase & 1023;
    const float* src = K + ((size_t)o << 20) + (size_t)d0 * ND + n;
    half8 v;
    #pragma unroll
    for (int j = 0; j < 8; ++j) v[j] = (_Float16)src[(size_t)j * ND];
    *(half8*)(Ktf + (size_t)gid * 8) = v;
}

// ---- persistent: flag-chained steps, no grid barrier, no release fences ----
// pcnt[t][64]: gemm completion, cell = nb*8 + (ks&7); target 8 (j<6) / 7 (j>=6)
// hcnt[t][16]: update completion, cell = blk&15; target 8
__global__ __launch_bounds__(256, 2) void persist_k(
    const float* __restrict__ signal, const _Float16* __restrict__ Ktf,
    const float* __restrict__ W, const float* __restrict__ operands,
    float* __restrict__ P, float* __restrict__ hbuf,
    float* __restrict__ out, unsigned* __restrict__ cells)
{
    __shared__ _Float16 lds_a[64 * 512];        // 64 KB frag-ordered A
    __shared__ _Float16 lds_b[2][8][512];       // 16 KB DMA double-buffer
    const int blk = blockIdx.x;
    const int nb = blk & 7, ks = blk >> 3;
    const int tid = threadIdx.x;
    const int l = tid & 63, w = tid >> 6;
    const int o = ks >> 1, d_base = (ks & 1) * 512;
    const int ml = l & 15, q = l >> 4;
    const int ns0 = nb * 8 + w * 2;
    const size_t kt0 = (size_t)ks * KC32;
    const int ab = tid >> 2, au = tid & 3;

    unsigned* pcnt = cells;                        // [16][64] stride CELL
    unsigned* hcnt = cells + NSTEPS * 64 * CELL;   // [16][16] stride CELL

    const _Float16* gB0 = Ktf + (((size_t)ns0 * KT32 + kt0) << 9) + (l << 3);
    const _Float16* gB1 = Ktf + ((((size_t)ns0 + 1) * KT32 + kt0) << 9) + (l << 3);
    float* Pks = P + (size_t)ks * (NB * ND);
    const half8* Ap = (const half8*)lds_a;

    const bool is_upd = (blk < 128);
    const int ub = blk >> 1, uhalf = blk & 1;      // updater: batch row, n-half

    #pragma unroll 1
    for (int t = 0; t < NSTEPS; ++t) {
        if (t > 0) {
            // wait for h_t (update of step t-1 complete), lanes 0..15 poll cells
            if (tid < 16) {
                unsigned* c = hcnt + (size_t)(t - 1) * 16 * CELL + tid * CELL;
                while (ld_rlx(c) < 8u) __builtin_amdgcn_s_sleep(8);
            }
            // acquire: buffer_inv only (no writeback) -> fresh h/P refills below
            __builtin_amdgcn_fence(__ATOMIC_ACQUIRE, "agent");
            __syncthreads();
        }
        const float* hsrc = (t == 0) ? signal : hbuf;

        // prefetch B chunks 0,1 (DMA; drained by post-A-stage __syncthreads)
        gld_lds16(gB0,       &lds_b[0][2 * w][0]);
        gld_lds16(gB1,       &lds_b[0][2 * w + 1][0]);
        gld_lds16(gB0 + 512, &lds_b[1][2 * w][0]);
        gld_lds16(gB1 + 512, &lds_b[1][2 * w + 1][0]);

        // ---- stage A: fp32 h * w -> fp16, frag-ordered ----
        {
            float wv = W[((size_t)ab * NSTEPS + t) * NO + o];
            const float* hb = hsrc + (size_t)ab * ND + d_base;
            #pragma unroll 4
            for (int li = 0; li < 16; ++li) {
                int p = li * 4 + au;
                float4 x0 = *(const float4*)(hb + p * 8);
                float4 x1 = *(const float4*)(hb + p * 8 + 4);
                half8 v;
                v[0] = (_Float16)(x0.x * wv); v[1] = (_Float16)(x0.y * wv);
                v[2] = (_Float16)(x0.z * wv); v[3] = (_Float16)(x0.w * wv);
                v[4] = (_Float16)(x1.x * wv); v[5] = (_Float16)(x1.y * wv);
                v[6] = (_Float16)(x1.z * wv); v[7] = (_Float16)(x1.w * wv);
                *(half8*)&lds_a[(size_t)(p * 64 + ab) * 8] = v;
            }
        }
        __syncthreads();

        floatx4 acc[2][4] = {};
        #pragma unroll
        for (int s = 0; s < 15; ++s) {
            wait_vm2();
            int buf = s & 1;
            half8 b0 = *(const half8*)&lds_b[buf][2 * w][l * 8];
            half8 b1 = *(const half8*)&lds_b[buf][2 * w + 1][l * 8];
            int abase = (s * 4 + q) * 64 + ml;
            half8 a0 = Ap[abase];
            half8 a1 = Ap[abase + 16];
            half8 a2 = Ap[abase + 32];
            half8 a3 = Ap[abase + 48];
            acc[0][0] = __builtin_amdgcn_mfma_f32_16x16x32_f16(a0, b0, acc[0][0], 0, 0, 0);
            acc[0][1] = __builtin_amdgcn_mfma_f32_16x16x32_f16(a1, b0, acc[0][1], 0, 0, 0);
            acc[0][2] = __builtin_amdgcn_mfma_f32_16x16x32_f16(a2, b0, acc[0][2], 0, 0, 0);
            acc[0][3] = __builtin_amdgcn_mfma_f32_16x16x32_f16(a3, b0, acc[0][3], 0, 0, 0);
            acc[1][0] = __builtin_amdgcn_mfma_f32_16x16x32_f16(a0, b1, acc[1][0], 0, 0, 0);
            acc[1][1] = __builtin_amdgcn_mfma_f32_16x16x32_f16(a1, b1, acc[1][1], 0, 0, 0);
            acc[1][2] = __builtin_amdgcn_mfma_f32_16x16x32_f16(a2, b1, acc[1][2], 0, 0, 0);
            acc[1][3] = __builtin_amdgcn_mfma_f32_16x16x32_f16(a3, b1, acc[1][3], 0, 0, 0);
            if (s < 14) {
                gld_lds16(gB0 + (size_t)(s + 2) * 512, &lds_b[buf][2 * w][0]);
                gld_lds16(gB1 + (size_t)(s + 2) * 512, &lds_b[buf][2 * w + 1][0]);
            }
        }
        {   // peeled s = 15
            wait_vm0();
            half8 b0 = *(const half8*)&lds_b[1][2 * w][l * 8];
            half8 b1 = *(const half8*)&lds_b[1][2 * w + 1][l * 8];
            int abase = (15 * 4 + q) * 64 + ml;
            half8 a0 = Ap[abase];
            half8 a1 = Ap[abase + 16];
            half8 a2 = Ap[abase + 32];
            half8 a3 = Ap[abase + 48];
            acc[0][0] = __builtin_amdgcn_mfma_f32_16x16x32_f16(a0, b0, acc[0][0], 0, 0, 0);
            acc[0][1] = __builtin_amdgcn_mfma_f32_16x16x32_f16(a1, b0, acc[0][1], 0, 0, 0);
            acc[0][2] = __builtin_amdgcn_mfma_f32_16x16x32_f16(a2, b0, acc[0][2], 0, 0, 0);
            acc[0][3] = __builtin_amdgcn_mfma_f32_16x16x32_f16(a3, b0, acc[0][3], 0, 0, 0);
            acc[1][0] = __builtin_amdgcn_mfma_f32_16x16x32_f16(a0, b1, acc[1][0], 0, 0, 0);
            acc[1][1] = __builtin_amdgcn_mfma_f32_16x16x32_f16(a1, b1, acc[1][1], 0, 0, 0);
            acc[1][2] = __builtin_amdgcn_mfma_f32_16x16x32_f16(a2, b1, acc[1][2], 0, 0, 0);
            acc[1][3] = __builtin_amdgcn_mfma_f32_16x16x32_f16(a3, b1, acc[1][3], 0, 0, 0);
        }

        // ---- write partial coherently (C/D: col = l&15, row = (l>>4)*4 + r) ----
        #pragma unroll
        for (int nsub = 0; nsub < 2; ++nsub) {
            int n = (ns0 + nsub) * 16 + ml;
            #pragma unroll
            for (int mt = 0; mt < 4; ++mt) {
                #pragma unroll
                for (int r = 0; r < 4; ++r) {
                    int b = mt * 16 + q * 4 + r;
                    stg_f(&Pks[(size_t)b * ND + n], acc[nsub][mt][r]);
                }
            }
        }
        __syncthreads();                       // all waves' stores drained (vmcnt 0)
        if (tid == 0)
            add_rlx(pcnt + (size_t)t * 64 * CELL + (nb * 8 + (ks & 7)) * CELL);

        // ---- update: 128 blocks, (b = blk>>1, n-half = blk&1) ----
        if (is_upd) {
            if (tid < 32) {                    // poll the 32 producer cells we need
                int cellidx = (uhalf * 4 + (tid >> 3)) * 8 + (tid & 7);
                unsigned tgt = ((tid & 7) < 6) ? 8u : 7u;
                unsigned* c = pcnt + (size_t)t * 64 * CELL + cellidx * CELL;
                while (ld_rlx(c) < tgt) __builtin_amdgcn_s_sleep(2);
            }
            __syncthreads();
            int n2 = uhalf * 512 + tid * 2;
            const float* prow = P + (size_t)ub * ND + n2;
            float sx = 0.f, sy = 0.f;
            #pragma unroll 8
            for (int k2 = 0; k2 < KS; ++k2) {
                float2 v = *(const float2*)(prow + (size_t)k2 * (NB * ND));
                sx += v.x; sy += v.y;
            }
            float gl = operands[((size_t)ub * NSTEPS + t) * 4 + 3];
            float g  = 1.0f / (1.0f + expf(-gl));
            float2 hv = *(const float2*)(hsrc + (size_t)ub * ND + n2);
            float2 ov;
            ov.x = g * sx + (1.f - g) * hv.x;
            ov.y = g * sy + (1.f - g) * hv.y;
            float* dst = (t == NSTEPS - 1) ? out : hbuf;
            stg_f2(dst + (size_t)ub * ND + n2, ov);
            __syncthreads();                   // drain h/out stores
            if (tid == 0 && t < NSTEPS - 1)
                add_rlx(hcnt + (size_t)t * 16 * CELL + (blk & 15) * CELL);
        }
    }
}

extern "C" void kernel_launch(void* const* d_in, const int* in_sizes, int n_in,
                              void* d_out, int out_size, void* d_ws, size_t ws_size,
                              hipStream_t stream)
{
    const float* logits   = (const float*)d_in[0];  // (64,16,31)
    const float* operands = (const float*)d_in[1];  // (64,16,4)
    const float* signal   = (const float*)d_in[2];  // (64,1024)
    const float* opk      = (const float*)d_in[3];  // (31,1024,1024)
    float* out = (float*)d_out;
    char* ws = (char*)d_ws;

    size_t offCNT = 0;                                 // 80 KB flag cells
    size_t offW   = 81920;                             // W: 126976 B
    size_t offP   = offW + 126976;                     // P: 62*64*1024*4
    size_t offH   = offP + (size_t)KS * NB * ND * 4;   // h: 256 KB
    size_t offK   = offH + (size_t)NB * ND * 4;        // Ktf: 62 MB fp16

    unsigned* cells = (unsigned*)(ws + offCNT);
    float*    W   = (float*)(ws + offW);
    float*    P   = (float*)(ws + offP);
    float*    h0  = (float*)(ws + offH);
    _Float16* Ktf = (_Float16*)(ws + offK);

    hipMemsetAsync(ws, 0, 81920, stream);   // zero flag cells
    softmax_k<<<dim3(4), 256, 0, stream>>>(logits, W);
    kconv_k<<<dim3(15872), 256, 0, stream>>>(opk, Ktf);
    persist_k<<<dim3(GRID), 256, 0, stream>>>(signal, Ktf, W, operands,
                                              P, h0, out, cells);
}